// Round 1
// baseline (598.219 us; speedup 1.0000x reference)
//
#include <hip/hip_runtime.h>
#include <cstdint>
#include <cstddef>

#define BB 4
#define NN 32768
#define PRE 4096
#define POST 512
#define NW 64   // u64 words per mask row = PRE/64

typedef unsigned long long u64;
typedef unsigned int u32;

__device__ __forceinline__ u32 enc_f32(float f) {
  u32 u = __float_as_uint(f);
  u32 m = (u32)((int)u >> 31) | 0x80000000u;  // neg -> 0xFFFFFFFF, pos -> 0x80000000
  return u ^ m;                                // ascending u <=> ascending f
}

// ---------------- kernel 1: scores = max over 3 classes, labels = argmax ----
__global__ void score_kernel(const float* __restrict__ cls,
                             float* __restrict__ scores, int* __restrict__ labels) {
  int g = blockIdx.x * blockDim.x + threadIdx.x;
  if (g >= BB * NN) return;
  const float* p = cls + (size_t)g * 3;
  float c0 = p[0], c1 = p[1], c2 = p[2];
  float m = c0; int l = 0;
  if (c1 > m) { m = c1; l = 1; }
  if (c2 > m) { m = c2; l = 2; }
  scores[g] = m;
  labels[g] = l;
}

// ---------------- kernel 2: per-batch radix-select top-PRE + bitonic sort ---
__global__ __launch_bounds__(1024) void select_kernel(
    const float* __restrict__ scores, const float* __restrict__ boxes,
    int* __restrict__ top_idx, float* __restrict__ top_score,
    float* __restrict__ bx1, float* __restrict__ bx2,
    float* __restrict__ by1, float* __restrict__ by2, float* __restrict__ bar) {
  int b = blockIdx.x;
  int tid = threadIdx.x;
  const float* sc = scores + (size_t)b * NN;

  __shared__ u32 hist[256];
  __shared__ u32 scanbuf[1024];
  __shared__ u64 sortbuf[PRE];
  __shared__ u32 sh_prefix;
  __shared__ int sh_rem;
  __shared__ int sh_gcnt;

  // --- 4-pass radix select of the PRE-th largest encoded score ---
  u32 prefix = 0, known = 0;
  int remaining = PRE;
  for (int shift = 24; shift >= 0; shift -= 8) {
    if (tid < 256) hist[tid] = 0;
    __syncthreads();
    for (int e = tid; e < NN; e += 1024) {
      u32 u = enc_f32(sc[e]);
      if ((u & known) == prefix) atomicAdd(&hist[(u >> shift) & 255u], 1u);
    }
    __syncthreads();
    if (tid == 0) {
      int acc = 0, bsel = 0;
      for (int v = 255; v >= 0; --v) {
        int h = (int)hist[v];
        if (acc + h >= remaining) { bsel = v; break; }
        acc += h;
      }
      sh_prefix = prefix | ((u32)bsel << shift);
      sh_rem = remaining - acc;  // how many pivot-valued elements still needed
    }
    __syncthreads();
    prefix = sh_prefix;
    remaining = sh_rem;
    known |= (0xFFu << shift);
    __syncthreads();
  }
  const u32 pivot = prefix;  // exact encoded value of the PRE-th largest

  // --- compaction: all u > pivot, plus `remaining` smallest-index u == pivot ---
  if (tid == 0) sh_gcnt = 0;
  __syncthreads();
  const int CH = NN / 1024;      // 32 contiguous elements per thread (index order)
  const int e0 = tid * CH;
  int eqc = 0;
  for (int k = 0; k < CH; ++k) {
    int e = e0 + k;
    u32 u = enc_f32(sc[e]);
    if (u > pivot) {
      int pos = atomicAdd(&sh_gcnt, 1);
      sortbuf[pos] = ((u64)u << 32) | (u32)(~(u32)e);
    } else if (u == pivot) {
      eqc++;
    }
  }
  __syncthreads();
  const int cnt_gt = sh_gcnt;    // == PRE - remaining
  scanbuf[tid] = (u32)eqc;
  __syncthreads();
  for (int off = 1; off < 1024; off <<= 1) {
    u32 v = scanbuf[tid];
    u32 add = (tid >= off) ? scanbuf[tid - off] : 0u;
    __syncthreads();
    scanbuf[tid] = v + add;
    __syncthreads();
  }
  int base = (int)scanbuf[tid] - eqc;  // exclusive rank (index-ordered) of my eq elems
  int rloc = 0;
  for (int k = 0; k < CH; ++k) {
    int e = e0 + k;
    u32 u = enc_f32(sc[e]);
    if (u == pivot) {
      int g = base + (rloc++);
      if (g < remaining) sortbuf[cnt_gt + g] = ((u64)u << 32) | (u32)(~(u32)e);
    }
  }
  __syncthreads();

  // --- bitonic sort sortbuf[PRE] descending (score desc, index asc on ties) ---
  for (int k = 2; k <= PRE; k <<= 1) {
    int jlg = 31 - __clz(k >> 1);
    for (int j = k >> 1; j > 0; j >>= 1, --jlg) {
      for (int p = tid; p < PRE / 2; p += 1024) {
        int i = ((p >> jlg) << (jlg + 1)) | (p & (j - 1));
        int ixj = i + j;
        u64 a = sortbuf[i], c = sortbuf[ixj];
        bool desc = ((i & k) == 0);
        bool sw = desc ? (a < c) : (a > c);
        if (sw) { sortbuf[i] = c; sortbuf[ixj] = a; }
      }
      __syncthreads();
    }
  }

  // --- epilogue: emit sorted indices/scores + box geometry ---
  {
#pragma clang fp contract(off)
    for (int s = tid; s < PRE; s += 1024) {
      u64 key = sortbuf[s];
      int e = (int)(~(u32)(key & 0xFFFFFFFFull));
      top_idx[b * PRE + s] = e;
      top_score[b * PRE + s] = sc[e];
      const float* bx = boxes + ((size_t)b * NN + e) * 7;
      float x = bx[0], y = bx[1], dx = bx[3], dy = bx[4];
      float hx = dx * 0.5f, hy = dy * 0.5f;
      bx1[b * PRE + s] = x - hx;
      bx2[b * PRE + s] = x + hx;
      by1[b * PRE + s] = y - hy;
      by2[b * PRE + s] = y + hy;
      bar[b * PRE + s] = dx * dy;
    }
  }
}

// ---------------- kernel 3: suppression bitmask (iou > 0.7, j > i) ----------
__global__ void mask_kernel(const float* __restrict__ bx1, const float* __restrict__ bx2,
                            const float* __restrict__ by1, const float* __restrict__ by2,
                            const float* __restrict__ bar, u64* __restrict__ mask) {
#pragma clang fp contract(off)
  int cb = blockIdx.x, rb = blockIdx.y, b = blockIdx.z;
  int t = threadIdx.x;
  int i = rb * 64 + t;
  u64* out = mask + ((size_t)b * PRE + i) * NW + cb;
  if (cb < rb) { *out = 0ull; return; }  // ws is poisoned: must write zeros

  __shared__ float sx1[64], sx2[64], sy1[64], sy2[64], sar[64];
  int j0 = cb * 64 + t;
  sx1[t] = bx1[b * PRE + j0];
  sx2[t] = bx2[b * PRE + j0];
  sy1[t] = by1[b * PRE + j0];
  sy2[t] = by2[b * PRE + j0];
  sar[t] = bar[b * PRE + j0];
  __syncthreads();

  float ix1 = bx1[b * PRE + i], ix2 = bx2[b * PRE + i];
  float iy1 = by1[b * PRE + i], iy2 = by2[b * PRE + i];
  float ia = bar[b * PRE + i];
  u64 bits = 0ull;
  int jbase = cb * 64;
  for (int jj = 0; jj < 64; ++jj) {
    int j = jbase + jj;
    if (j > i) {
      float iw = fminf(ix2, sx2[jj]) - fmaxf(ix1, sx1[jj]);
      iw = fmaxf(iw, 0.0f);
      float ih = fminf(iy2, sy2[jj]) - fmaxf(iy1, sy1[jj]);
      ih = fmaxf(ih, 0.0f);
      float inter = iw * ih;
      float uni = ia + sar[jj] - inter;
      float den = fmaxf(uni, 1e-6f);
      float iou = inter / den;
      if (iou > 0.7f) bits |= (1ull << jj);
    }
  }
  *out = bits;
}

// ---------------- kernel 4: serial greedy NMS, one wave per batch -----------
__global__ void nms_kernel(const u64* __restrict__ mask, u64* __restrict__ keep_words) {
  int b = blockIdx.x;
  int lane = threadIdx.x;  // 64 lanes = 1 wave, lane w owns suppression word w
  const u64* row = mask + (size_t)b * PRE * NW;
  u64 rem = 0ull, keepw = 0ull;
  constexpr int D = 16;  // prefetch depth (static ring: rule #20)
  u64 pf[D];
#pragma unroll
  for (int d = 0; d < D; ++d) pf[d] = row[(size_t)d * NW + lane];
  for (int ii = 0; ii < PRE; ii += D) {
#pragma unroll
    for (int d = 0; d < D; ++d) {
      int i = ii + d;
      int owner = i >> 6;
      u32 mybit = (u32)((rem >> (i & 63)) & 1ull);
      u32 ob = (u32)__shfl((int)mybit, owner, 64);
      u64 r = pf[d];
      int nxt = i + D;
      if (nxt > PRE - 1) nxt = PRE - 1;
      pf[d] = row[(size_t)nxt * NW + lane];
      if (ob == 0u) {            // box i kept: it suppresses its mask row
        rem |= r;
        if (lane == owner) keepw |= (1ull << (i & 63));
      }
    }
  }
  keep_words[b * 64 + lane] = keepw;
}

// ---------------- kernel 5: emit first POST kept entries --------------------
__global__ __launch_bounds__(1024) void output_kernel(
    const u64* __restrict__ keep_words, const int* __restrict__ top_idx,
    const float* __restrict__ top_score, const int* __restrict__ labels,
    const float* __restrict__ boxes, float* __restrict__ out) {
  int b = blockIdx.x, tid = threadIdx.x;
  __shared__ u32 scanbuf[1024];
  __shared__ int sh_total;

  u64 w = keep_words[b * 64 + (tid >> 4)];
  u32 my4 = (u32)((w >> ((tid & 15) * 4)) & 0xFull);  // 4 consecutive i per thread
  int cnt = __popc(my4);
  scanbuf[tid] = (u32)cnt;
  __syncthreads();
  for (int off = 1; off < 1024; off <<= 1) {
    u32 v = scanbuf[tid];
    u32 add = (tid >= off) ? scanbuf[tid - off] : 0u;
    __syncthreads();
    scanbuf[tid] = v + add;
    __syncthreads();
  }
  int base = (int)scanbuf[tid] - cnt;
  if (tid == 1023) sh_total = (int)scanbuf[1023];
  __syncthreads();
  int total = sh_total;

  float* rois = out;                          // BB*POST*7
  float* rsc = out + BB * POST * 7;           // BB*POST
  float* rlb = rsc + BB * POST;               // BB*POST (labels as f32)

  int r = 0;
  for (int k = 0; k < 4; ++k) {
    if ((my4 >> k) & 1u) {
      int rank = base + (r++);
      if (rank < POST) {
        int i = tid * 4 + k;
        int idx = top_idx[b * PRE + i];
        const float* bx = boxes + ((size_t)b * NN + idx) * 7;
        float* ro = rois + ((size_t)b * POST + rank) * 7;
        for (int c = 0; c < 7; ++c) ro[c] = bx[c];
        rsc[b * POST + rank] = top_score[b * PRE + i];
        rlb[b * POST + rank] = (float)(labels[b * NN + idx] + 1);
      }
    }
  }
  // invalid slots: rois = 0, score = 0, label = 0 + 1
  for (int s = tid; s < POST; s += 1024) {
    if (s >= total) {
      float* ro = rois + ((size_t)b * POST + s) * 7;
      for (int c = 0; c < 7; ++c) ro[c] = 0.0f;
      rsc[b * POST + s] = 0.0f;
      rlb[b * POST + s] = 1.0f;
    }
  }
}

// ---------------------------------------------------------------------------
extern "C" void kernel_launch(void* const* d_in, const int* in_sizes, int n_in,
                              void* d_out, int out_size, void* d_ws, size_t ws_size,
                              hipStream_t stream) {
  const float* boxes = (const float*)d_in[0];  // (B, N, 7)
  const float* cls = (const float*)d_in[1];    // (B, N, 3)
  float* out = (float*)d_out;                  // rois | scores | labels, flat f32

  char* w = (char*)d_ws;
  float* scores = (float*)w;    w += (size_t)BB * NN * 4;
  int* labels = (int*)w;        w += (size_t)BB * NN * 4;
  int* top_idx = (int*)w;       w += (size_t)BB * PRE * 4;
  float* top_score = (float*)w; w += (size_t)BB * PRE * 4;
  float* bx1 = (float*)w;       w += (size_t)BB * PRE * 4;
  float* bx2 = (float*)w;       w += (size_t)BB * PRE * 4;
  float* by1 = (float*)w;       w += (size_t)BB * PRE * 4;
  float* by2 = (float*)w;       w += (size_t)BB * PRE * 4;
  float* bar = (float*)w;       w += (size_t)BB * PRE * 4;
  u64* mask = (u64*)w;          w += (size_t)BB * PRE * NW * 8;
  u64* keepw = (u64*)w;         w += (size_t)BB * 64 * 8;

  score_kernel<<<(BB * NN + 255) / 256, 256, 0, stream>>>(cls, scores, labels);
  select_kernel<<<BB, 1024, 0, stream>>>(scores, boxes, top_idx, top_score,
                                         bx1, bx2, by1, by2, bar);
  mask_kernel<<<dim3(NW, PRE / 64, BB), 64, 0, stream>>>(bx1, bx2, by1, by2, bar, mask);
  nms_kernel<<<BB, 64, 0, stream>>>(mask, keepw);
  output_kernel<<<BB, 1024, 0, stream>>>(keepw, top_idx, top_score, labels, boxes, out);
}

// Round 2
// 498.872 us; speedup vs baseline: 1.1991x; 1.1991x over previous
//
#include <hip/hip_runtime.h>
#include <cstdint>
#include <cstddef>

#define BB 4
#define NN 32768
#define PRE 4096
#define POST 512
#define NW 64   // u64 words per mask row = PRE/64

typedef unsigned long long u64;
typedef unsigned int u32;

__device__ __forceinline__ u32 enc_f32(float f) {
  u32 u = __float_as_uint(f);
  u32 m = (u32)((int)u >> 31) | 0x80000000u;  // neg -> 0xFFFFFFFF, pos -> 0x80000000
  return u ^ m;                                // ascending u <=> ascending f
}

// ---------------- kernel 1: scores = max over 3 classes, labels = argmax ----
__global__ void score_kernel(const float* __restrict__ cls,
                             float* __restrict__ scores, int* __restrict__ labels) {
  int g = blockIdx.x * blockDim.x + threadIdx.x;
  if (g >= BB * NN) return;
  const float* p = cls + (size_t)g * 3;
  float c0 = p[0], c1 = p[1], c2 = p[2];
  float m = c0; int l = 0;
  if (c1 > m) { m = c1; l = 1; }
  if (c2 > m) { m = c2; l = 2; }
  scores[g] = m;
  labels[g] = l;
}

// ---------------- kernel 2: per-batch radix-select top-PRE + bitonic sort ---
__global__ __launch_bounds__(1024) void select_kernel(
    const float* __restrict__ scores, const float* __restrict__ boxes,
    int* __restrict__ top_idx, float* __restrict__ top_score,
    float* __restrict__ bx1, float* __restrict__ bx2,
    float* __restrict__ by1, float* __restrict__ by2, float* __restrict__ bar) {
  int b = blockIdx.x;
  int tid = threadIdx.x;
  const float* sc = scores + (size_t)b * NN;

  __shared__ u32 hist[256];
  __shared__ u32 scanbuf[1024];
  __shared__ u64 sortbuf[PRE];
  __shared__ u32 sh_prefix;
  __shared__ int sh_rem;
  __shared__ int sh_gcnt;

  // --- 4-pass radix select of the PRE-th largest encoded score ---
  u32 prefix = 0, known = 0;
  int remaining = PRE;
  for (int shift = 24; shift >= 0; shift -= 8) {
    if (tid < 256) hist[tid] = 0;
    __syncthreads();
    for (int e = tid; e < NN; e += 1024) {
      u32 u = enc_f32(sc[e]);
      if ((u & known) == prefix) atomicAdd(&hist[(u >> shift) & 255u], 1u);
    }
    __syncthreads();
    if (tid == 0) {
      int acc = 0, bsel = 0;
      for (int v = 255; v >= 0; --v) {
        int h = (int)hist[v];
        if (acc + h >= remaining) { bsel = v; break; }
        acc += h;
      }
      sh_prefix = prefix | ((u32)bsel << shift);
      sh_rem = remaining - acc;  // how many pivot-valued elements still needed
    }
    __syncthreads();
    prefix = sh_prefix;
    remaining = sh_rem;
    known |= (0xFFu << shift);
    __syncthreads();
  }
  const u32 pivot = prefix;  // exact encoded value of the PRE-th largest

  // --- compaction: all u > pivot, plus `remaining` smallest-index u == pivot ---
  if (tid == 0) sh_gcnt = 0;
  __syncthreads();
  const int CH = NN / 1024;      // 32 contiguous elements per thread (index order)
  const int e0 = tid * CH;
  int eqc = 0;
  for (int k = 0; k < CH; ++k) {
    int e = e0 + k;
    u32 u = enc_f32(sc[e]);
    if (u > pivot) {
      int pos = atomicAdd(&sh_gcnt, 1);
      sortbuf[pos] = ((u64)u << 32) | (u32)(~(u32)e);
    } else if (u == pivot) {
      eqc++;
    }
  }
  __syncthreads();
  const int cnt_gt = sh_gcnt;    // == PRE - remaining
  scanbuf[tid] = (u32)eqc;
  __syncthreads();
  for (int off = 1; off < 1024; off <<= 1) {
    u32 v = scanbuf[tid];
    u32 add = (tid >= off) ? scanbuf[tid - off] : 0u;
    __syncthreads();
    scanbuf[tid] = v + add;
    __syncthreads();
  }
  int base = (int)scanbuf[tid] - eqc;  // exclusive rank (index-ordered) of my eq elems
  int rloc = 0;
  for (int k = 0; k < CH; ++k) {
    int e = e0 + k;
    u32 u = enc_f32(sc[e]);
    if (u == pivot) {
      int g = base + (rloc++);
      if (g < remaining) sortbuf[cnt_gt + g] = ((u64)u << 32) | (u32)(~(u32)e);
    }
  }
  __syncthreads();

  // --- bitonic sort sortbuf[PRE] descending (score desc, index asc on ties) ---
  for (int k = 2; k <= PRE; k <<= 1) {
    int jlg = 31 - __clz(k >> 1);
    for (int j = k >> 1; j > 0; j >>= 1, --jlg) {
      for (int p = tid; p < PRE / 2; p += 1024) {
        int i = ((p >> jlg) << (jlg + 1)) | (p & (j - 1));
        int ixj = i + j;
        u64 a = sortbuf[i], c = sortbuf[ixj];
        bool desc = ((i & k) == 0);
        bool sw = desc ? (a < c) : (a > c);
        if (sw) { sortbuf[i] = c; sortbuf[ixj] = a; }
      }
      __syncthreads();
    }
  }

  // --- epilogue: emit sorted indices/scores + box geometry ---
  {
#pragma clang fp contract(off)
    for (int s = tid; s < PRE; s += 1024) {
      u64 key = sortbuf[s];
      int e = (int)(~(u32)(key & 0xFFFFFFFFull));
      top_idx[b * PRE + s] = e;
      top_score[b * PRE + s] = sc[e];
      const float* bx = boxes + ((size_t)b * NN + e) * 7;
      float x = bx[0], y = bx[1], dx = bx[3], dy = bx[4];
      float hx = dx * 0.5f, hy = dy * 0.5f;
      bx1[b * PRE + s] = x - hx;
      bx2[b * PRE + s] = x + hx;
      by1[b * PRE + s] = y - hy;
      by2[b * PRE + s] = y + hy;
      bar[b * PRE + s] = dx * dy;
    }
  }
}

// ---------------- kernel 3: suppression bitmask (iou > 0.7, j > i) ----------
__global__ void mask_kernel(const float* __restrict__ bx1, const float* __restrict__ bx2,
                            const float* __restrict__ by1, const float* __restrict__ by2,
                            const float* __restrict__ bar, u64* __restrict__ mask) {
#pragma clang fp contract(off)
  int cb = blockIdx.x, rb = blockIdx.y, b = blockIdx.z;
  int t = threadIdx.x;
  int i = rb * 64 + t;
  u64* out = mask + ((size_t)b * PRE + i) * NW + cb;
  if (cb < rb) { *out = 0ull; return; }  // ws is poisoned: must write zeros

  __shared__ float sx1[64], sx2[64], sy1[64], sy2[64], sar[64];
  int j0 = cb * 64 + t;
  sx1[t] = bx1[b * PRE + j0];
  sx2[t] = bx2[b * PRE + j0];
  sy1[t] = by1[b * PRE + j0];
  sy2[t] = by2[b * PRE + j0];
  sar[t] = bar[b * PRE + j0];
  __syncthreads();

  float ix1 = bx1[b * PRE + i], ix2 = bx2[b * PRE + i];
  float iy1 = by1[b * PRE + i], iy2 = by2[b * PRE + i];
  float ia = bar[b * PRE + i];
  u64 bits = 0ull;
  int jbase = cb * 64;
  for (int jj = 0; jj < 64; ++jj) {
    int j = jbase + jj;
    if (j > i) {
      float iw = fminf(ix2, sx2[jj]) - fmaxf(ix1, sx1[jj]);
      iw = fmaxf(iw, 0.0f);
      float ih = fminf(iy2, sy2[jj]) - fmaxf(iy1, sy1[jj]);
      ih = fmaxf(ih, 0.0f);
      float inter = iw * ih;
      float uni = ia + sar[jj] - inter;
      float den = fmaxf(uni, 1e-6f);
      float iou = inter / den;
      if (iou > 0.7f) bits |= (1ull << jj);
    }
  }
  *out = bits;
}

// ---------------- kernel 4: chunked greedy NMS, one wave per batch ----------
// Chunk = 64 boxes = one u64 keep word. Per chunk:
//  - broadcast running suppression word remc for this chunk (1 shfl64)
//  - each lane loads the diagonal word of "its" row; ballot finds rows that
//    can suppress within-chunk (rare with this data) -> short serial loop
//  - K = ~remc (bit i final once row i processed, since mask has only j>i)
//  - data-parallel: lane w ORs mask[row][w] over kept rows into its rem word
__global__ void nms_kernel(const u64* __restrict__ mask, u64* __restrict__ keep_words) {
  int b = blockIdx.x;
  int lane = threadIdx.x;  // 64 lanes = 1 wave; lane w owns suppression word w
  const u64* base = mask + (size_t)b * PRE * NW;
  u64 rem = 0ull, keepw = 0ull;

  for (int c = 0; c < NW; ++c) {
    // running suppression state for this chunk's 64 boxes
    u64 remc = __shfl(rem, c, 64);
    // diagonal word of row (c*64+lane): within-chunk suppression candidates
    u64 dg = base[((size_t)(c * 64 + lane)) * NW + c];
    u64 nz = __ballot(dg != 0ull);
    // serial resolution over the (rare) rows that suppress within the chunk
    while (nz) {
      int i = __builtin_ctzll(nz);
      nz &= nz - 1ull;
      u64 di = __shfl(dg, i, 64);
      if (!((remc >> i) & 1ull)) remc |= di;
    }
    u64 K = ~remc;  // keep word for this chunk
    if (lane == c) keepw = K;

    // accumulate cross-chunk suppression: rem |= OR_{kept i} mask[c*64+i][lane]
    const u64* rowp = base + ((size_t)(c * 64)) * NW + lane;
    if (K == ~0ull) {
      u64 a0 = 0, a1 = 0, a2 = 0, a3 = 0, a4 = 0, a5 = 0, a6 = 0, a7 = 0;
#pragma unroll
      for (int i = 0; i < 64; i += 8) {
        a0 |= rowp[(size_t)(i + 0) * NW];
        a1 |= rowp[(size_t)(i + 1) * NW];
        a2 |= rowp[(size_t)(i + 2) * NW];
        a3 |= rowp[(size_t)(i + 3) * NW];
        a4 |= rowp[(size_t)(i + 4) * NW];
        a5 |= rowp[(size_t)(i + 5) * NW];
        a6 |= rowp[(size_t)(i + 6) * NW];
        a7 |= rowp[(size_t)(i + 7) * NW];
      }
      rem |= (a0 | a1) | (a2 | a3) | ((a4 | a5) | (a6 | a7));
    } else {
      u64 a0 = 0, a1 = 0, a2 = 0, a3 = 0;
#pragma unroll
      for (int i = 0; i < 64; i += 4) {
        u64 m0 = rowp[(size_t)(i + 0) * NW];
        u64 m1 = rowp[(size_t)(i + 1) * NW];
        u64 m2 = rowp[(size_t)(i + 2) * NW];
        u64 m3 = rowp[(size_t)(i + 3) * NW];
        if ((K >> (i + 0)) & 1ull) a0 |= m0;
        if ((K >> (i + 1)) & 1ull) a1 |= m1;
        if ((K >> (i + 2)) & 1ull) a2 |= m2;
        if ((K >> (i + 3)) & 1ull) a3 |= m3;
      }
      rem |= (a0 | a1) | (a2 | a3);
    }
  }
  keep_words[b * 64 + lane] = keepw;
}

// ---------------- kernel 5: emit first POST kept entries --------------------
__global__ __launch_bounds__(1024) void output_kernel(
    const u64* __restrict__ keep_words, const int* __restrict__ top_idx,
    const float* __restrict__ top_score, const int* __restrict__ labels,
    const float* __restrict__ boxes, float* __restrict__ out) {
  int b = blockIdx.x, tid = threadIdx.x;
  __shared__ u32 scanbuf[1024];
  __shared__ int sh_total;

  u64 w = keep_words[b * 64 + (tid >> 4)];
  u32 my4 = (u32)((w >> ((tid & 15) * 4)) & 0xFull);  // 4 consecutive i per thread
  int cnt = __popc(my4);
  scanbuf[tid] = (u32)cnt;
  __syncthreads();
  for (int off = 1; off < 1024; off <<= 1) {
    u32 v = scanbuf[tid];
    u32 add = (tid >= off) ? scanbuf[tid - off] : 0u;
    __syncthreads();
    scanbuf[tid] = v + add;
    __syncthreads();
  }
  int base = (int)scanbuf[tid] - cnt;
  if (tid == 1023) sh_total = (int)scanbuf[1023];
  __syncthreads();
  int total = sh_total;

  float* rois = out;                          // BB*POST*7
  float* rsc = out + BB * POST * 7;           // BB*POST
  float* rlb = rsc + BB * POST;               // BB*POST (labels as f32)

  int r = 0;
  for (int k = 0; k < 4; ++k) {
    if ((my4 >> k) & 1u) {
      int rank = base + (r++);
      if (rank < POST) {
        int i = tid * 4 + k;
        int idx = top_idx[b * PRE + i];
        const float* bx = boxes + ((size_t)b * NN + idx) * 7;
        float* ro = rois + ((size_t)b * POST + rank) * 7;
        for (int c = 0; c < 7; ++c) ro[c] = bx[c];
        rsc[b * POST + rank] = top_score[b * PRE + i];
        rlb[b * POST + rank] = (float)(labels[b * NN + idx] + 1);
      }
    }
  }
  // invalid slots: rois = 0, score = 0, label = 0 + 1
  for (int s = tid; s < POST; s += 1024) {
    if (s >= total) {
      float* ro = rois + ((size_t)b * POST + s) * 7;
      for (int c = 0; c < 7; ++c) ro[c] = 0.0f;
      rsc[b * POST + s] = 0.0f;
      rlb[b * POST + s] = 1.0f;
    }
  }
}

// ---------------------------------------------------------------------------
extern "C" void kernel_launch(void* const* d_in, const int* in_sizes, int n_in,
                              void* d_out, int out_size, void* d_ws, size_t ws_size,
                              hipStream_t stream) {
  const float* boxes = (const float*)d_in[0];  // (B, N, 7)
  const float* cls = (const float*)d_in[1];    // (B, N, 3)
  float* out = (float*)d_out;                  // rois | scores | labels, flat f32

  char* w = (char*)d_ws;
  float* scores = (float*)w;    w += (size_t)BB * NN * 4;
  int* labels = (int*)w;        w += (size_t)BB * NN * 4;
  int* top_idx = (int*)w;       w += (size_t)BB * PRE * 4;
  float* top_score = (float*)w; w += (size_t)BB * PRE * 4;
  float* bx1 = (float*)w;       w += (size_t)BB * PRE * 4;
  float* bx2 = (float*)w;       w += (size_t)BB * PRE * 4;
  float* by1 = (float*)w;       w += (size_t)BB * PRE * 4;
  float* by2 = (float*)w;       w += (size_t)BB * PRE * 4;
  float* bar = (float*)w;       w += (size_t)BB * PRE * 4;
  u64* mask = (u64*)w;          w += (size_t)BB * PRE * NW * 8;
  u64* keepw = (u64*)w;         w += (size_t)BB * 64 * 8;

  score_kernel<<<(BB * NN + 255) / 256, 256, 0, stream>>>(cls, scores, labels);
  select_kernel<<<BB, 1024, 0, stream>>>(scores, boxes, top_idx, top_score,
                                         bx1, bx2, by1, by2, bar);
  mask_kernel<<<dim3(NW, PRE / 64, BB), 64, 0, stream>>>(bx1, bx2, by1, by2, bar, mask);
  nms_kernel<<<BB, 64, 0, stream>>>(mask, keepw);
  output_kernel<<<BB, 1024, 0, stream>>>(keepw, top_idx, top_score, labels, boxes, out);
}

// Round 3
// 217.423 us; speedup vs baseline: 2.7514x; 2.2945x over previous
//
#include <hip/hip_runtime.h>
#include <cstdint>
#include <cstddef>

#define BB 4
#define NN 32768
#define PRE 4096
#define POST 512
#define NW 64        // u64 words per mask row = PRE/64
#define PREF_CH 16   // prefix chunks computed eagerly (1024 rows)

typedef unsigned long long u64;
typedef unsigned int u32;

__device__ __forceinline__ u32 enc_f32(float f) {
  u32 u = __float_as_uint(f);
  u32 m = (u32)((int)u >> 31) | 0x80000000u;  // neg -> 0xFFFFFFFF, pos -> 0x80000000
  return u ^ m;                                // ascending u <=> ascending f
}

// ---------------- kernel 1: scores = max over 3 classes, labels = argmax ----
__global__ void score_kernel(const float* __restrict__ cls,
                             float* __restrict__ scores, int* __restrict__ labels) {
  int g = blockIdx.x * blockDim.x + threadIdx.x;
  if (g >= BB * NN) return;
  const float* p = cls + (size_t)g * 3;
  float c0 = p[0], c1 = p[1], c2 = p[2];
  float m = c0; int l = 0;
  if (c1 > m) { m = c1; l = 1; }
  if (c2 > m) { m = c2; l = 2; }
  scores[g] = m;
  labels[g] = l;
}

// ---------------- kernel 2: per-batch radix-select top-PRE + bitonic sort ---
__global__ __launch_bounds__(1024) void select_kernel(
    const float* __restrict__ scores, const float* __restrict__ boxes,
    int* __restrict__ top_idx, float* __restrict__ top_score,
    float* __restrict__ bx1, float* __restrict__ bx2,
    float* __restrict__ by1, float* __restrict__ by2, float* __restrict__ bar) {
  int b = blockIdx.x;
  int tid = threadIdx.x;
  const float* sc = scores + (size_t)b * NN;

  __shared__ u32 hist[256];
  __shared__ u32 scanbuf[1024];
  __shared__ u64 sortbuf[PRE];
  __shared__ u32 sh_prefix;
  __shared__ int sh_rem;
  __shared__ int sh_gcnt;

  // --- 4-pass radix select of the PRE-th largest encoded score ---
  u32 prefix = 0, known = 0;
  int remaining = PRE;
  for (int shift = 24; shift >= 0; shift -= 8) {
    if (tid < 256) hist[tid] = 0;
    __syncthreads();
    for (int e = tid; e < NN; e += 1024) {
      u32 u = enc_f32(sc[e]);
      if ((u & known) == prefix) atomicAdd(&hist[(u >> shift) & 255u], 1u);
    }
    __syncthreads();
    if (tid == 0) {
      int acc = 0, bsel = 0;
      for (int v = 255; v >= 0; --v) {
        int h = (int)hist[v];
        if (acc + h >= remaining) { bsel = v; break; }
        acc += h;
      }
      sh_prefix = prefix | ((u32)bsel << shift);
      sh_rem = remaining - acc;  // how many pivot-valued elements still needed
    }
    __syncthreads();
    prefix = sh_prefix;
    remaining = sh_rem;
    known |= (0xFFu << shift);
    __syncthreads();
  }
  const u32 pivot = prefix;  // exact encoded value of the PRE-th largest

  // --- compaction: all u > pivot, plus `remaining` smallest-index u == pivot ---
  if (tid == 0) sh_gcnt = 0;
  __syncthreads();
  const int CH = NN / 1024;      // 32 contiguous elements per thread (index order)
  const int e0 = tid * CH;
  int eqc = 0;
  for (int k = 0; k < CH; ++k) {
    int e = e0 + k;
    u32 u = enc_f32(sc[e]);
    if (u > pivot) {
      int pos = atomicAdd(&sh_gcnt, 1);
      sortbuf[pos] = ((u64)u << 32) | (u32)(~(u32)e);
    } else if (u == pivot) {
      eqc++;
    }
  }
  __syncthreads();
  const int cnt_gt = sh_gcnt;    // == PRE - remaining
  scanbuf[tid] = (u32)eqc;
  __syncthreads();
  for (int off = 1; off < 1024; off <<= 1) {
    u32 v = scanbuf[tid];
    u32 add = (tid >= off) ? scanbuf[tid - off] : 0u;
    __syncthreads();
    scanbuf[tid] = v + add;
    __syncthreads();
  }
  int base = (int)scanbuf[tid] - eqc;  // exclusive rank (index-ordered) of my eq elems
  int rloc = 0;
  for (int k = 0; k < CH; ++k) {
    int e = e0 + k;
    u32 u = enc_f32(sc[e]);
    if (u == pivot) {
      int g = base + (rloc++);
      if (g < remaining) sortbuf[cnt_gt + g] = ((u64)u << 32) | (u32)(~(u32)e);
    }
  }
  __syncthreads();

  // --- bitonic sort sortbuf[PRE] descending (score desc, index asc on ties) ---
  for (int k = 2; k <= PRE; k <<= 1) {
    int jlg = 31 - __clz(k >> 1);
    for (int j = k >> 1; j > 0; j >>= 1, --jlg) {
      for (int p = tid; p < PRE / 2; p += 1024) {
        int i = ((p >> jlg) << (jlg + 1)) | (p & (j - 1));
        int ixj = i + j;
        u64 a = sortbuf[i], c = sortbuf[ixj];
        bool desc = ((i & k) == 0);
        bool sw = desc ? (a < c) : (a > c);
        if (sw) { sortbuf[i] = c; sortbuf[ixj] = a; }
      }
      __syncthreads();
    }
  }

  // --- epilogue: emit sorted indices/scores + box geometry ---
  {
#pragma clang fp contract(off)
    for (int s = tid; s < PRE; s += 1024) {
      u64 key = sortbuf[s];
      int e = (int)(~(u32)(key & 0xFFFFFFFFull));
      top_idx[b * PRE + s] = e;
      top_score[b * PRE + s] = sc[e];
      const float* bx = boxes + ((size_t)b * NN + e) * 7;
      float x = bx[0], y = bx[1], dx = bx[3], dy = bx[4];
      float hx = dx * 0.5f, hy = dy * 0.5f;
      bx1[b * PRE + s] = x - hx;
      bx2[b * PRE + s] = x + hx;
      by1[b * PRE + s] = y - hy;
      by2[b * PRE + s] = y + hy;
      bar[b * PRE + s] = dx * dy;
    }
  }
}

// ---------------- kernel 3: suppression bitmask (iou > 0.7, j > i) ----------
// rows [rb0*64, (rb0+gridDim.y)*64), all 64 column words.
__device__ __forceinline__ void mask_body(
    const float* __restrict__ bx1, const float* __restrict__ bx2,
    const float* __restrict__ by1, const float* __restrict__ by2,
    const float* __restrict__ bar, u64* __restrict__ mask, int rb0) {
#pragma clang fp contract(off)
  int cb = blockIdx.x, rb = rb0 + blockIdx.y, b = blockIdx.z;
  int t = threadIdx.x;
  int i = rb * 64 + t;
  u64* out = mask + ((size_t)b * PRE + i) * NW + cb;
  if (cb < rb) { *out = 0ull; return; }  // ws is poisoned: must write zeros

  __shared__ float sx1[64], sx2[64], sy1[64], sy2[64], sar[64];
  int j0 = cb * 64 + t;
  sx1[t] = bx1[b * PRE + j0];
  sx2[t] = bx2[b * PRE + j0];
  sy1[t] = by1[b * PRE + j0];
  sy2[t] = by2[b * PRE + j0];
  sar[t] = bar[b * PRE + j0];
  __syncthreads();

  float ix1 = bx1[b * PRE + i], ix2 = bx2[b * PRE + i];
  float iy1 = by1[b * PRE + i], iy2 = by2[b * PRE + i];
  float ia = bar[b * PRE + i];
  u64 bits = 0ull;
  int jbase = cb * 64;
  for (int jj = 0; jj < 64; ++jj) {
    int j = jbase + jj;
    if (j > i) {
      float iw = fminf(ix2, sx2[jj]) - fmaxf(ix1, sx1[jj]);
      iw = fmaxf(iw, 0.0f);
      float ih = fminf(iy2, sy2[jj]) - fmaxf(iy1, sy1[jj]);
      ih = fmaxf(ih, 0.0f);
      float inter = iw * ih;
      float uni = ia + sar[jj] - inter;
      float den = fmaxf(uni, 1e-6f);
      float iou = inter / den;
      if (iou > 0.7f) bits |= (1ull << jj);
    }
  }
  *out = bits;
}

__global__ void mask_prefix_kernel(const float* __restrict__ bx1, const float* __restrict__ bx2,
                                   const float* __restrict__ by1, const float* __restrict__ by2,
                                   const float* __restrict__ bar, u64* __restrict__ mask) {
  mask_body(bx1, bx2, by1, by2, bar, mask, 0);
}

// tail: only runs if the prefix pass did not find POST keepers
__global__ void mask_tail_kernel(const float* __restrict__ bx1, const float* __restrict__ bx2,
                                 const float* __restrict__ by1, const float* __restrict__ by2,
                                 const float* __restrict__ bar, u64* __restrict__ mask,
                                 const int* __restrict__ st_info) {
  if (st_info[blockIdx.z * 2 + 0] >= POST) return;
  mask_body(bx1, bx2, by1, by2, bar, mask, PREF_CH);
}

// ---------------- kernel 4: chunked greedy NMS, 4 waves per batch -----------
// Chunk = 64 boxes = one u64 keep word. Per chunk:
//  - all waves issue 16 ungated row loads (mask[row][lane], coalesced)
//  - all waves redundantly load the diagonal word + serial-resolve the (rare)
//    within-chunk suppressions -> keep word K (identical across waves)
//  - each wave ORs its 16 rows gated by K; partials combined via LDS
// Early-stop once cumulative kept >= POST (later output ranks >= POST).
__global__ __launch_bounds__(256) void nms_range_kernel(
    const u64* __restrict__ mask, u64* __restrict__ keep_words,
    u64* __restrict__ st_rem, int* __restrict__ st_info, int phase) {
  int b = blockIdx.x;
  int tid = threadIdx.x;
  int lane = tid & 63;
  int wv = tid >> 6;
  __shared__ u64 part[2][4][64];

  const u64* base = mask + (size_t)b * PRE * NW;
  u64 rem, keepw = 0ull;
  int kept, c0, c1;
  if (phase == 0) {
    rem = 0ull; kept = 0; c0 = 0; c1 = PREF_CH;
  } else {
    kept = st_info[b * 2 + 0];
    c0 = st_info[b * 2 + 1];
    if (kept >= POST) return;
    rem = st_rem[b * 64 + lane];
    c1 = NW;
  }

  int c = c0;
  while (c < c1) {
    u64 remc = __shfl(rem, c, 64);
    // ungated row loads for my wave's 16 rows (static addresses, issue early)
    const u64* rowp = base + ((size_t)(c * 64 + wv * 16)) * NW + lane;
    u64 m[16];
#pragma unroll
    for (int k = 0; k < 16; ++k) m[k] = rowp[(size_t)k * NW];
    // diagonal word of row (c*64+lane): within-chunk suppression candidates
    u64 dg = base[((size_t)(c * 64 + lane)) * NW + c];
    u64 nz = __ballot(dg != 0ull);
    while (nz) {
      int i = __builtin_ctzll(nz);
      nz &= nz - 1ull;
      u64 di = __shfl(dg, i, 64);
      if (!((remc >> i) & 1ull)) remc |= di;
    }
    u64 K = ~remc;  // keep word for this chunk (identical in all waves)
    if (lane == c) keepw = K;
    kept += __popcll(K);

    // gated OR of my wave's 16 rows into partial, combine via LDS
    u32 kb = (u32)((K >> (wv * 16)) & 0xFFFFull);
    u64 acc = 0ull;
#pragma unroll
    for (int k = 0; k < 16; ++k)
      if ((kb >> k) & 1u) acc |= m[k];
    part[c & 1][wv][lane] = acc;
    __syncthreads();
    rem |= part[c & 1][0][lane] | part[c & 1][1][lane] |
           part[c & 1][2][lane] | part[c & 1][3][lane];
    ++c;
    if (kept >= POST) break;  // uniform across block
  }

  // keep words: phase 0 writes all lanes (zeros beyond processed chunks);
  // phase 1 overwrites only the chunks it processed.
  if (wv == 0) {
    if (phase == 0 || (lane >= c0 && lane < c))
      keep_words[b * 64 + lane] = keepw;
    if (phase == 0) {
      st_rem[b * 64 + lane] = rem;
      if (lane == 0) { st_info[b * 2 + 0] = kept; st_info[b * 2 + 1] = c; }
    }
  }
}

// ---------------- kernel 5: emit first POST kept entries --------------------
__global__ __launch_bounds__(1024) void output_kernel(
    const u64* __restrict__ keep_words, const int* __restrict__ top_idx,
    const float* __restrict__ top_score, const int* __restrict__ labels,
    const float* __restrict__ boxes, float* __restrict__ out) {
  int b = blockIdx.x, tid = threadIdx.x;
  __shared__ u32 scanbuf[1024];
  __shared__ int sh_total;

  u64 w = keep_words[b * 64 + (tid >> 4)];
  u32 my4 = (u32)((w >> ((tid & 15) * 4)) & 0xFull);  // 4 consecutive i per thread
  int cnt = __popc(my4);
  scanbuf[tid] = (u32)cnt;
  __syncthreads();
  for (int off = 1; off < 1024; off <<= 1) {
    u32 v = scanbuf[tid];
    u32 add = (tid >= off) ? scanbuf[tid - off] : 0u;
    __syncthreads();
    scanbuf[tid] = v + add;
    __syncthreads();
  }
  int base = (int)scanbuf[tid] - cnt;
  if (tid == 1023) sh_total = (int)scanbuf[1023];
  __syncthreads();
  int total = sh_total;

  float* rois = out;                          // BB*POST*7
  float* rsc = out + BB * POST * 7;           // BB*POST
  float* rlb = rsc + BB * POST;               // BB*POST (labels as f32)

  int r = 0;
  for (int k = 0; k < 4; ++k) {
    if ((my4 >> k) & 1u) {
      int rank = base + (r++);
      if (rank < POST) {
        int i = tid * 4 + k;
        int idx = top_idx[b * PRE + i];
        const float* bx = boxes + ((size_t)b * NN + idx) * 7;
        float* ro = rois + ((size_t)b * POST + rank) * 7;
        for (int c = 0; c < 7; ++c) ro[c] = bx[c];
        rsc[b * POST + rank] = top_score[b * PRE + i];
        rlb[b * POST + rank] = (float)(labels[b * NN + idx] + 1);
      }
    }
  }
  // invalid slots: rois = 0, score = 0, label = 0 + 1
  for (int s = tid; s < POST; s += 1024) {
    if (s >= total) {
      float* ro = rois + ((size_t)b * POST + s) * 7;
      for (int c = 0; c < 7; ++c) ro[c] = 0.0f;
      rsc[b * POST + s] = 0.0f;
      rlb[b * POST + s] = 1.0f;
    }
  }
}

// ---------------------------------------------------------------------------
extern "C" void kernel_launch(void* const* d_in, const int* in_sizes, int n_in,
                              void* d_out, int out_size, void* d_ws, size_t ws_size,
                              hipStream_t stream) {
  const float* boxes = (const float*)d_in[0];  // (B, N, 7)
  const float* cls = (const float*)d_in[1];    // (B, N, 3)
  float* out = (float*)d_out;                  // rois | scores | labels, flat f32

  char* w = (char*)d_ws;
  float* scores = (float*)w;    w += (size_t)BB * NN * 4;
  int* labels = (int*)w;        w += (size_t)BB * NN * 4;
  int* top_idx = (int*)w;       w += (size_t)BB * PRE * 4;
  float* top_score = (float*)w; w += (size_t)BB * PRE * 4;
  float* bx1 = (float*)w;       w += (size_t)BB * PRE * 4;
  float* bx2 = (float*)w;       w += (size_t)BB * PRE * 4;
  float* by1 = (float*)w;       w += (size_t)BB * PRE * 4;
  float* by2 = (float*)w;       w += (size_t)BB * PRE * 4;
  float* bar = (float*)w;       w += (size_t)BB * PRE * 4;
  u64* mask = (u64*)w;          w += (size_t)BB * PRE * NW * 8;
  u64* keepw = (u64*)w;         w += (size_t)BB * 64 * 8;
  u64* st_rem = (u64*)w;        w += (size_t)BB * 64 * 8;
  int* st_info = (int*)w;       w += (size_t)BB * 2 * 4;

  score_kernel<<<(BB * NN + 255) / 256, 256, 0, stream>>>(cls, scores, labels);
  select_kernel<<<BB, 1024, 0, stream>>>(scores, boxes, top_idx, top_score,
                                         bx1, bx2, by1, by2, bar);
  mask_prefix_kernel<<<dim3(NW, PREF_CH, BB), 64, 0, stream>>>(bx1, bx2, by1, by2, bar, mask);
  nms_range_kernel<<<BB, 256, 0, stream>>>(mask, keepw, st_rem, st_info, 0);
  mask_tail_kernel<<<dim3(NW, NW - PREF_CH, BB), 64, 0, stream>>>(bx1, bx2, by1, by2, bar,
                                                                  mask, st_info);
  nms_range_kernel<<<BB, 256, 0, stream>>>(mask, keepw, st_rem, st_info, 1);
  output_kernel<<<BB, 1024, 0, stream>>>(keepw, top_idx, top_score, labels, boxes, out);
}

// Round 4
// 140.690 us; speedup vs baseline: 4.2520x; 1.5454x over previous
//
#include <hip/hip_runtime.h>
#include <cstdint>
#include <cstddef>

#define BB 4
#define NN 32768
#define PRE 4096
#define POST 512
#define NW 64        // u64 words per full mask row = PRE/64
#define PSEL 1024    // prefix selection size (hot path)
#define PREF_CH 16   // PSEL/64 chunks

typedef unsigned long long u64;
typedef unsigned int u32;

// LDS bank-conflict swizzle for the u64 sort buffer
#define SW(i) ((i) ^ (((i) >> 4) & 15))

__device__ __forceinline__ u32 enc_f32(float f) {
  u32 u = __float_as_uint(f);
  u32 m = (u32)((int)u >> 31) | 0x80000000u;  // neg -> 0xFFFFFFFF, pos -> 0x80000000
  return u ^ m;                                // ascending u <=> ascending f
}

// ---------------- kernel 1: scores = max over 3 classes, labels = argmax ----
__global__ void score_kernel(const float* __restrict__ cls,
                             float* __restrict__ scores, int* __restrict__ labels) {
  int g = blockIdx.x * blockDim.x + threadIdx.x;
  if (g >= BB * NN) return;
  const float* p = cls + (size_t)g * 3;
  float c0 = p[0], c1 = p[1], c2 = p[2];
  float m = c0; int l = 0;
  if (c1 > m) { m = c1; l = 1; }
  if (c2 > m) { m = c2; l = 2; }
  scores[g] = m;
  labels[g] = l;
}

// ------- kernel 2: per-batch radix-select top-SELN + swizzled bitonic sort --
template<int SELN, bool GATED>
__global__ __launch_bounds__(1024) void select_kernel_t(
    const float* __restrict__ scores, const float* __restrict__ boxes,
    const int* __restrict__ st_info,
    int* __restrict__ top_idx, float* __restrict__ top_score,
    float* __restrict__ bx1, float* __restrict__ bx2,
    float* __restrict__ by1, float* __restrict__ by2, float* __restrict__ bar) {
  int b = blockIdx.x;
  if (GATED && st_info[b * 2 + 0] >= POST) return;  // fallback not needed
  int tid = threadIdx.x;
  int wv = tid >> 6;
  const float* sc = scores + (size_t)b * NN;

  __shared__ u32 hist16[16][256];   // per-wave privatized histograms
  __shared__ u32 sA[256], sB[256];  // suffix-scan ping-pong
  __shared__ u32 scanbuf[1024];
  __shared__ u64 sortbuf[SELN];
  __shared__ u32 sh_prefix;
  __shared__ int sh_rem;

  // --- load my 32 contiguous scores ONCE into registers (reused 6x) ---
  const int e0 = tid * 32;
  u32 encs[32];
  {
    const float4* sc4 = (const float4*)(sc + e0);
#pragma unroll
    for (int k = 0; k < 8; ++k) {
      float4 v = sc4[k];
      encs[k * 4 + 0] = enc_f32(v.x);
      encs[k * 4 + 1] = enc_f32(v.y);
      encs[k * 4 + 2] = enc_f32(v.z);
      encs[k * 4 + 3] = enc_f32(v.w);
    }
  }

  // --- 4-pass radix select of the SELN-th largest encoded score ---
  u32 prefix = 0, known = 0;
  int remaining = SELN;
  for (int shift = 24; shift >= 0; shift -= 8) {
    for (int k = tid; k < 16 * 256; k += 1024) ((u32*)hist16)[k] = 0;
    __syncthreads();
#pragma unroll
    for (int k = 0; k < 32; ++k) {
      u32 u = encs[k];
      if ((u & known) == prefix) atomicAdd(&hist16[wv][(u >> shift) & 255u], 1u);
    }
    __syncthreads();
    if (tid < 256) {
      u32 t = 0;
#pragma unroll
      for (int w2 = 0; w2 < 16; ++w2) t += hist16[w2][tid];
      sA[tid] = t;
    }
    __syncthreads();
    // parallel inclusive suffix-scan over 256 bins
    u32* src = sA; u32* dst = sB;
    for (int off = 1; off < 256; off <<= 1) {
      if (tid < 256) dst[tid] = src[tid] + ((tid + off < 256) ? src[tid + off] : 0u);
      __syncthreads();
      u32* tp = src; src = dst; dst = tp;
    }
    if (tid < 256) {
      u32 sv = src[tid];
      u32 svn = (tid < 255) ? src[tid + 1] : 0u;
      if (sv >= (u32)remaining && svn < (u32)remaining) {  // unique crossing bin
        sh_prefix = prefix | ((u32)tid << shift);
        sh_rem = remaining - (int)svn;
      }
    }
    __syncthreads();
    prefix = sh_prefix;
    remaining = sh_rem;
    known |= (0xFFu << shift);
    __syncthreads();
  }
  const u32 pivot = prefix;

  // --- compaction via positional packed scan (stable for ==pivot) ---
  int gtc = 0, eqc = 0;
#pragma unroll
  for (int k = 0; k < 32; ++k) {
    gtc += (encs[k] > pivot);
    eqc += (encs[k] == pivot);
  }
  scanbuf[tid] = ((u32)gtc << 16) | (u32)eqc;
  __syncthreads();
  for (int off = 1; off < 1024; off <<= 1) {
    u32 v = scanbuf[tid];
    u32 add = (tid >= off) ? scanbuf[tid - off] : 0u;
    __syncthreads();
    scanbuf[tid] = v + add;
    __syncthreads();
  }
  u32 incl = scanbuf[tid];
  u32 totpk = scanbuf[1023];
  const int cnt_gt = (int)(totpk >> 16);         // == SELN - remaining
  int gt_base = (int)(incl >> 16) - gtc;
  int eq_base = (int)(incl & 0xFFFFu) - eqc;
  int gs = 0, es = 0;
#pragma unroll
  for (int k = 0; k < 32; ++k) {
    u32 u = encs[k];
    int e = e0 + k;
    u64 key = ((u64)u << 32) | (u32)(~(u32)e);
    if (u > pivot) {
      sortbuf[SW(gt_base + gs)] = key; gs++;
    } else if (u == pivot) {
      int g = eq_base + es; es++;
      if (g < remaining) sortbuf[SW(cnt_gt + g)] = key;
    }
  }
  __syncthreads();

  // --- bitonic sort (descending), swizzled LDS accesses ---
  for (int k = 2; k <= SELN; k <<= 1) {
    for (int j = k >> 1; j > 0; j >>= 1) {
      for (int p = tid; p < SELN / 2; p += 1024) {
        int low = p & (j - 1);
        int i = ((p ^ low) << 1) | low;
        int ixj = i + j;
        u64 a = sortbuf[SW(i)], c = sortbuf[SW(ixj)];
        bool desc = ((i & k) == 0);
        if (desc ? (a < c) : (a > c)) { sortbuf[SW(i)] = c; sortbuf[SW(ixj)] = a; }
      }
      __syncthreads();
    }
  }

  // --- epilogue: emit sorted indices/scores + box geometry ---
  {
#pragma clang fp contract(off)
    for (int s = tid; s < SELN; s += 1024) {
      u64 key = sortbuf[SW(s)];
      int e = (int)(~(u32)(key & 0xFFFFFFFFull));
      top_idx[b * PRE + s] = e;
      top_score[b * PRE + s] = sc[e];
      const float* bx = boxes + ((size_t)b * NN + e) * 7;
      float x = bx[0], y = bx[1], dx = bx[3], dy = bx[4];
      float hx = dx * 0.5f, hy = dy * 0.5f;
      bx1[b * PRE + s] = x - hx;
      bx2[b * PRE + s] = x + hx;
      by1[b * PRE + s] = y - hy;
      by2[b * PRE + s] = y + hy;
      bar[b * PRE + s] = dx * dy;
    }
  }
}

// ---------------- kernel 3: suppression bitmask (iou > 0.7, j > i) ----------
// One wave computes one 64x64 tile (row-block rb x column-word cb) via shfl
// broadcast of the column boxes -- no LDS, no barriers. Lower-triangle words
// (cb < rb) are never consumed by the NMS pass, so they are skipped entirely.
__device__ __forceinline__ void mask_tile(
    const float* __restrict__ bx1, const float* __restrict__ bx2,
    const float* __restrict__ by1, const float* __restrict__ by2,
    const float* __restrict__ bar, u64* __restrict__ mask,
    int b, int rb, int cb, int t) {
#pragma clang fp contract(off)
  int i = rb * 64 + t;
  int j0 = cb * 64 + t;
  float cx1 = bx1[b * PRE + j0], cx2 = bx2[b * PRE + j0];
  float cy1 = by1[b * PRE + j0], cy2 = by2[b * PRE + j0];
  float car = bar[b * PRE + j0];
  float ix1 = bx1[b * PRE + i], ix2 = bx2[b * PRE + i];
  float iy1 = by1[b * PRE + i], iy2 = by2[b * PRE + i];
  float ia = bar[b * PRE + i];
  u64 bits = 0ull;
  int jbase = cb * 64;
  for (int jj = 0; jj < 64; ++jj) {
    float jx1 = __shfl(cx1, jj, 64);
    float jx2 = __shfl(cx2, jj, 64);
    float jy1 = __shfl(cy1, jj, 64);
    float jy2 = __shfl(cy2, jj, 64);
    float jar = __shfl(car, jj, 64);
    if (jbase + jj > i) {
      float iw = fminf(ix2, jx2) - fmaxf(ix1, jx1);
      iw = fmaxf(iw, 0.0f);
      float ih = fminf(iy2, jy2) - fmaxf(iy1, jy1);
      ih = fmaxf(ih, 0.0f);
      float inter = iw * ih;
      float uni = ia + jar - inter;
      float iou = inter / fmaxf(uni, 1e-6f);
      if (iou > 0.7f) bits |= (1ull << jj);
    }
  }
  mask[((size_t)b * PRE + i) * NW + cb] = bits;
}

__global__ void mask_prefix_kernel(const float* __restrict__ bx1, const float* __restrict__ bx2,
                                   const float* __restrict__ by1, const float* __restrict__ by2,
                                   const float* __restrict__ bar, u64* __restrict__ mask) {
  int cb = blockIdx.x, rb = blockIdx.y, b = blockIdx.z;
  if (cb < rb) return;
  mask_tile(bx1, bx2, by1, by2, bar, mask, b, rb, cb, threadIdx.x);
}

// fallback: full 4096x4096 mask; 4 column words per 256-thr block (wave each)
__global__ __launch_bounds__(256) void mask_full_kernel(
    const float* __restrict__ bx1, const float* __restrict__ bx2,
    const float* __restrict__ by1, const float* __restrict__ by2,
    const float* __restrict__ bar, u64* __restrict__ mask,
    const int* __restrict__ st_info) {
  int b = blockIdx.z;
  if (st_info[b * 2 + 0] >= POST) return;
  int rb = blockIdx.y;
  int cb = blockIdx.x * 4 + (threadIdx.x >> 6);
  if (cb < rb) return;
  mask_tile(bx1, bx2, by1, by2, bar, mask, b, rb, cb, threadIdx.x & 63);
}

// ---------------- kernel 4: chunked greedy NMS, 4 waves per batch -----------
template<bool FULL>
__global__ __launch_bounds__(256) void nms_kernel_t(
    const u64* __restrict__ mask, u64* __restrict__ keep_words,
    int* __restrict__ st_info) {
  int b = blockIdx.x;
  if (FULL && st_info[b * 2 + 0] >= POST) return;  // hot path already done
  int tid = threadIdx.x;
  int lane = tid & 63;
  int wv = tid >> 6;
  __shared__ u64 part[2][4][64];

  const u64* base = mask + (size_t)b * PRE * NW;
  u64 rem = 0ull, keepw = 0ull;
  int kept = 0;
  const int c1 = FULL ? NW : PREF_CH;

  int c = 0;
  while (c < c1) {
    u64 remc = __shfl(rem, c, 64);
    // ungated row loads for my wave's 16 rows (issue before dependent work)
    const u64* rowp = base + ((size_t)(c * 64 + wv * 16)) * NW + lane;
    u64 m[16];
#pragma unroll
    for (int k = 0; k < 16; ++k) m[k] = rowp[(size_t)k * NW];
    // diagonal word: within-chunk suppression candidates (rare)
    u64 dg = base[((size_t)(c * 64 + lane)) * NW + c];
    u64 nz = __ballot(dg != 0ull);
    while (nz) {
      int i2 = __builtin_ctzll(nz);
      nz &= nz - 1ull;
      u64 di = __shfl(dg, i2, 64);
      if (!((remc >> i2) & 1ull)) remc |= di;
    }
    u64 K = ~remc;  // keep word for this chunk (identical in all waves)
    if (lane == c) keepw = K;
    kept += __popcll(K);

    u32 kb = (u32)((K >> (wv * 16)) & 0xFFFFull);
    u64 acc = 0ull;
#pragma unroll
    for (int k = 0; k < 16; ++k)
      if ((kb >> k) & 1u) acc |= m[k];
    part[c & 1][wv][lane] = acc;
    __syncthreads();
    rem |= part[c & 1][0][lane] | part[c & 1][1][lane] |
           part[c & 1][2][lane] | part[c & 1][3][lane];
    ++c;
    if (kept >= POST) break;  // uniform; later output ranks all >= POST
  }

  if (wv == 0) {
    keep_words[b * 64 + lane] = keepw;  // unprocessed chunks -> 0
    if (!FULL && lane == 0) st_info[b * 2 + 0] = kept;
  }
}

// ---------------- kernel 5: emit first POST kept entries --------------------
__global__ __launch_bounds__(1024) void output_kernel(
    const u64* __restrict__ keep_words, const int* __restrict__ top_idx,
    const float* __restrict__ top_score, const int* __restrict__ labels,
    const float* __restrict__ boxes, float* __restrict__ out) {
  int b = blockIdx.x, tid = threadIdx.x;
  __shared__ u32 scanbuf[1024];
  __shared__ int sh_total;

  u64 w = keep_words[b * 64 + (tid >> 4)];
  u32 my4 = (u32)((w >> ((tid & 15) * 4)) & 0xFull);  // 4 consecutive i per thread
  int cnt = __popc(my4);
  scanbuf[tid] = (u32)cnt;
  __syncthreads();
  for (int off = 1; off < 1024; off <<= 1) {
    u32 v = scanbuf[tid];
    u32 add = (tid >= off) ? scanbuf[tid - off] : 0u;
    __syncthreads();
    scanbuf[tid] = v + add;
    __syncthreads();
  }
  int base = (int)scanbuf[tid] - cnt;
  if (tid == 1023) sh_total = (int)scanbuf[1023];
  __syncthreads();
  int total = sh_total;

  float* rois = out;                          // BB*POST*7
  float* rsc = out + BB * POST * 7;           // BB*POST
  float* rlb = rsc + BB * POST;               // BB*POST (labels as f32)

  int r = 0;
  for (int k = 0; k < 4; ++k) {
    if ((my4 >> k) & 1u) {
      int rank = base + (r++);
      if (rank < POST) {
        int i = tid * 4 + k;
        int idx = top_idx[b * PRE + i];
        const float* bx = boxes + ((size_t)b * NN + idx) * 7;
        float* ro = rois + ((size_t)b * POST + rank) * 7;
        for (int c = 0; c < 7; ++c) ro[c] = bx[c];
        rsc[b * POST + rank] = top_score[b * PRE + i];
        rlb[b * POST + rank] = (float)(labels[b * NN + idx] + 1);
      }
    }
  }
  // invalid slots: rois = 0, score = 0, label = 0 + 1
  for (int s = tid; s < POST; s += 1024) {
    if (s >= total) {
      float* ro = rois + ((size_t)b * POST + s) * 7;
      for (int c = 0; c < 7; ++c) ro[c] = 0.0f;
      rsc[b * POST + s] = 0.0f;
      rlb[b * POST + s] = 1.0f;
    }
  }
}

// ---------------------------------------------------------------------------
extern "C" void kernel_launch(void* const* d_in, const int* in_sizes, int n_in,
                              void* d_out, int out_size, void* d_ws, size_t ws_size,
                              hipStream_t stream) {
  const float* boxes = (const float*)d_in[0];  // (B, N, 7)
  const float* cls = (const float*)d_in[1];    // (B, N, 3)
  float* out = (float*)d_out;                  // rois | scores | labels, flat f32

  char* w = (char*)d_ws;
  float* scores = (float*)w;    w += (size_t)BB * NN * 4;
  int* labels = (int*)w;        w += (size_t)BB * NN * 4;
  int* top_idx = (int*)w;       w += (size_t)BB * PRE * 4;
  float* top_score = (float*)w; w += (size_t)BB * PRE * 4;
  float* bx1 = (float*)w;       w += (size_t)BB * PRE * 4;
  float* bx2 = (float*)w;       w += (size_t)BB * PRE * 4;
  float* by1 = (float*)w;       w += (size_t)BB * PRE * 4;
  float* by2 = (float*)w;       w += (size_t)BB * PRE * 4;
  float* bar = (float*)w;       w += (size_t)BB * PRE * 4;
  u64* mask = (u64*)w;          w += (size_t)BB * PRE * NW * 8;
  u64* keepw = (u64*)w;         w += (size_t)BB * 64 * 8;
  int* st_info = (int*)w;       w += (size_t)BB * 2 * 4;

  // hot path: top-1024 prefix only
  score_kernel<<<(BB * NN + 255) / 256, 256, 0, stream>>>(cls, scores, labels);
  select_kernel_t<PSEL, false><<<BB, 1024, 0, stream>>>(
      scores, boxes, st_info, top_idx, top_score, bx1, bx2, by1, by2, bar);
  mask_prefix_kernel<<<dim3(PREF_CH, PREF_CH, BB), 64, 0, stream>>>(
      bx1, bx2, by1, by2, bar, mask);
  nms_kernel_t<false><<<BB, 256, 0, stream>>>(mask, keepw, st_info);
  // fallback chain (exits immediately when prefix found >= POST keepers)
  select_kernel_t<PRE, true><<<BB, 1024, 0, stream>>>(
      scores, boxes, st_info, top_idx, top_score, bx1, bx2, by1, by2, bar);
  mask_full_kernel<<<dim3(NW / 4, NW, BB), 256, 0, stream>>>(
      bx1, bx2, by1, by2, bar, mask, st_info);
  nms_kernel_t<true><<<BB, 256, 0, stream>>>(mask, keepw, st_info);
  // output
  output_kernel<<<BB, 1024, 0, stream>>>(keepw, top_idx, top_score, labels, boxes, out);
}

// Round 6
// 134.429 us; speedup vs baseline: 4.4501x; 1.0466x over previous
//
#include <hip/hip_runtime.h>
#include <cstdint>
#include <cstddef>

#define BB 4
#define NN 32768
#define PRE 4096
#define POST 512
#define NW 64        // u64 words per full mask row = PRE/64
#define PSEL 1024    // prefix selection size (hot path)
#define PREF_CH 16   // PSEL/64 chunks

typedef unsigned long long u64;
typedef unsigned int u32;

// LDS bank-conflict swizzle for the fallback's u64 sort buffer
#define SW(i) ((i) ^ (((i) >> 4) & 15))

__device__ __forceinline__ u32 enc_f32(float f) {
  u32 u = __float_as_uint(f);
  u32 m = (u32)((int)u >> 31) | 0x80000000u;  // neg -> 0xFFFFFFFF, pos -> 0x80000000
  return u ^ m;                                // ascending u <=> ascending f
}

// ---------------- kernel 1: scores = max over 3 classes, labels = argmax ----
__global__ void score_kernel(const float* __restrict__ cls,
                             float* __restrict__ scores, int* __restrict__ labels) {
  int g = blockIdx.x * blockDim.x + threadIdx.x;
  if (g >= BB * NN) return;
  const float* p = cls + (size_t)g * 3;
  float c0 = p[0], c1 = p[1], c2 = p[2];
  float m = c0; int l = 0;
  if (c1 > m) { m = c1; l = 1; }
  if (c2 > m) { m = c2; l = 2; }
  scores[g] = m;
  labels[g] = l;
}

// ------- kernel 2: per-batch radix-select top-SELN + bitonic sort -----------
// SELN==PSEL (hot): linear sortbuf + hybrid 1-elem/thread sort
//   (shfl_xor for j<64 — no LDS/barriers; LDS exchange only for j>=64).
// SELN==PRE (gated fallback): round-4 strided sort with SW swizzle (proven).
template<int SELN, bool GATED>
__global__ __launch_bounds__(1024) void select_kernel_t(
    const float* __restrict__ scores, const float* __restrict__ boxes,
    const int* __restrict__ st_info,
    int* __restrict__ top_idx, float* __restrict__ top_score,
    float* __restrict__ bx1, float* __restrict__ bx2,
    float* __restrict__ by1, float* __restrict__ by2, float* __restrict__ bar) {
  constexpr bool HY = (SELN == PSEL);
  int b = blockIdx.x;
  if (GATED && st_info[b * 2 + 0] >= POST) return;  // fallback not needed
  int tid = threadIdx.x;
  int wv = tid >> 6;
  const float* sc = scores + (size_t)b * NN;

  __shared__ u32 hist16[16][256];   // per-wave privatized histograms
  __shared__ u32 sA[256], sB[256];  // suffix-scan ping-pong
  __shared__ u32 scanbuf[1024];
  __shared__ u64 sortbuf[SELN];
  __shared__ u32 sh_prefix;
  __shared__ int sh_rem;

  // --- load my 32 contiguous scores ONCE into registers (reused 6x) ---
  const int e0 = tid * 32;
  u32 encs[32];
  {
    const float4* sc4 = (const float4*)(sc + e0);
#pragma unroll
    for (int k = 0; k < 8; ++k) {
      float4 v = sc4[k];
      encs[k * 4 + 0] = enc_f32(v.x);
      encs[k * 4 + 1] = enc_f32(v.y);
      encs[k * 4 + 2] = enc_f32(v.z);
      encs[k * 4 + 3] = enc_f32(v.w);
    }
  }

  // --- 4-pass radix select of the SELN-th largest encoded score ---
  u32 prefix = 0, known = 0;
  int remaining = SELN;
  for (int shift = 24; shift >= 0; shift -= 8) {
    for (int k = tid; k < 16 * 256; k += 1024) ((u32*)hist16)[k] = 0;
    __syncthreads();
#pragma unroll
    for (int k = 0; k < 32; ++k) {
      u32 u = encs[k];
      if ((u & known) == prefix) atomicAdd(&hist16[wv][(u >> shift) & 255u], 1u);
    }
    __syncthreads();
    if (tid < 256) {
      u32 t = 0;
#pragma unroll
      for (int w2 = 0; w2 < 16; ++w2) t += hist16[w2][tid];
      sA[tid] = t;
    }
    __syncthreads();
    // parallel inclusive suffix-scan over 256 bins
    u32* src = sA; u32* dst = sB;
    for (int off = 1; off < 256; off <<= 1) {
      if (tid < 256) dst[tid] = src[tid] + ((tid + off < 256) ? src[tid + off] : 0u);
      __syncthreads();
      u32* tp = src; src = dst; dst = tp;
    }
    if (tid < 256) {
      u32 sv = src[tid];
      u32 svn = (tid < 255) ? src[tid + 1] : 0u;
      if (sv >= (u32)remaining && svn < (u32)remaining) {  // unique crossing bin
        sh_prefix = prefix | ((u32)tid << shift);
        sh_rem = remaining - (int)svn;
      }
    }
    __syncthreads();
    prefix = sh_prefix;
    remaining = sh_rem;
    known |= (0xFFu << shift);
    __syncthreads();
  }
  const u32 pivot = prefix;

  // --- compaction via positional packed scan (stable for ==pivot) ---
  int gtc = 0, eqc = 0;
#pragma unroll
  for (int k = 0; k < 32; ++k) {
    gtc += (encs[k] > pivot);
    eqc += (encs[k] == pivot);
  }
  scanbuf[tid] = ((u32)gtc << 16) | (u32)eqc;
  __syncthreads();
  for (int off = 1; off < 1024; off <<= 1) {
    u32 v = scanbuf[tid];
    u32 add = (tid >= off) ? scanbuf[tid - off] : 0u;
    __syncthreads();
    scanbuf[tid] = v + add;
    __syncthreads();
  }
  u32 incl = scanbuf[tid];
  u32 totpk = scanbuf[1023];
  const int cnt_gt = (int)(totpk >> 16);         // == SELN - remaining
  int gt_base = (int)(incl >> 16) - gtc;
  int eq_base = (int)(incl & 0xFFFFu) - eqc;
  int gs = 0, es = 0;
#pragma unroll
  for (int k = 0; k < 32; ++k) {
    u32 u = encs[k];
    int e = e0 + k;
    u64 key = ((u64)u << 32) | (u32)(~(u32)e);
    if (u > pivot) {
      int pos = gt_base + (gs++);
      sortbuf[HY ? pos : SW(pos)] = key;
    } else if (u == pivot) {
      int g = eq_base + (es++);
      if (g < remaining) {
        int pos = cnt_gt + g;
        sortbuf[HY ? pos : SW(pos)] = key;
      }
    }
  }
  __syncthreads();

  if constexpr (HY) {
    // --- hybrid bitonic sort, 1 elem/thread (SELN == 1024 == blockDim) ---
    u64 key = sortbuf[tid];
#pragma unroll
    for (int k2 = 2; k2 <= 64; k2 <<= 1) {
      for (int j = k2 >> 1; j > 0; j >>= 1) {
        u64 o = __shfl_xor(key, j, 64);
        bool take_max = (((tid & k2) == 0) == ((tid & j) == 0));
        key = ((key > o) == take_max) ? key : o;
      }
    }
    for (int k2 = 128; k2 <= PSEL; k2 <<= 1) {
      for (int j = k2 >> 1; j >= 64; j >>= 1) {
        __syncthreads();
        sortbuf[tid] = key;
        __syncthreads();
        u64 o = sortbuf[tid ^ j];
        bool take_max = (((tid & k2) == 0) == ((tid & j) == 0));
        key = ((key > o) == take_max) ? key : o;
      }
      for (int j = 32; j > 0; j >>= 1) {
        u64 o = __shfl_xor(key, j, 64);
        bool take_max = (((tid & k2) == 0) == ((tid & j) == 0));
        key = ((key > o) == take_max) ? key : o;
      }
    }
    // --- epilogue: one sorted element per thread ---
    {
#pragma clang fp contract(off)
      int e = (int)(~(u32)(key & 0xFFFFFFFFull));
      top_idx[b * PRE + tid] = e;
      top_score[b * PRE + tid] = sc[e];
      const float* bx = boxes + ((size_t)b * NN + e) * 7;
      float x = bx[0], y = bx[1], dx = bx[3], dy = bx[4];
      float hx = dx * 0.5f, hy = dy * 0.5f;
      bx1[b * PRE + tid] = x - hx;
      bx2[b * PRE + tid] = x + hx;
      by1[b * PRE + tid] = y - hy;
      by2[b * PRE + tid] = y + hy;
      bar[b * PRE + tid] = dx * dy;
    }
  } else {
    // --- round-4 strided bitonic sort (descending), swizzled LDS ---
    for (int k = 2; k <= SELN; k <<= 1) {
      for (int j = k >> 1; j > 0; j >>= 1) {
        for (int p = tid; p < SELN / 2; p += 1024) {
          int low = p & (j - 1);
          int i = ((p ^ low) << 1) | low;
          int ixj = i + j;
          u64 a = sortbuf[SW(i)], c = sortbuf[SW(ixj)];
          bool desc = ((i & k) == 0);
          if (desc ? (a < c) : (a > c)) { sortbuf[SW(i)] = c; sortbuf[SW(ixj)] = a; }
        }
        __syncthreads();
      }
    }
    {
#pragma clang fp contract(off)
      for (int s = tid; s < SELN; s += 1024) {
        u64 key = sortbuf[SW(s)];
        int e = (int)(~(u32)(key & 0xFFFFFFFFull));
        top_idx[b * PRE + s] = e;
        top_score[b * PRE + s] = sc[e];
        const float* bx = boxes + ((size_t)b * NN + e) * 7;
        float x = bx[0], y = bx[1], dx = bx[3], dy = bx[4];
        float hx = dx * 0.5f, hy = dy * 0.5f;
        bx1[b * PRE + s] = x - hx;
        bx2[b * PRE + s] = x + hx;
        by1[b * PRE + s] = y - hy;
        by2[b * PRE + s] = y + hy;
        bar[b * PRE + s] = dx * dy;
      }
    }
  }
}

// ---------------- kernel 3: suppression bitmask (iou > 0.7, j > i) ----------
// One wave computes one 64x64 tile (row-block rb x column-word cb) via shfl
// broadcast of the column boxes -- no LDS, no barriers. Lower-triangle words
// (cb < rb) are never consumed by the NMS pass, so they are skipped entirely.
__device__ __forceinline__ void mask_tile(
    const float* __restrict__ bx1, const float* __restrict__ bx2,
    const float* __restrict__ by1, const float* __restrict__ by2,
    const float* __restrict__ bar, u64* __restrict__ mask,
    int b, int rb, int cb, int t) {
#pragma clang fp contract(off)
  int i = rb * 64 + t;
  int j0 = cb * 64 + t;
  float cx1 = bx1[b * PRE + j0], cx2 = bx2[b * PRE + j0];
  float cy1 = by1[b * PRE + j0], cy2 = by2[b * PRE + j0];
  float car = bar[b * PRE + j0];
  float ix1 = bx1[b * PRE + i], ix2 = bx2[b * PRE + i];
  float iy1 = by1[b * PRE + i], iy2 = by2[b * PRE + i];
  float ia = bar[b * PRE + i];
  u64 bits = 0ull;
  int jbase = cb * 64;
  for (int jj = 0; jj < 64; ++jj) {
    float jx1 = __shfl(cx1, jj, 64);
    float jx2 = __shfl(cx2, jj, 64);
    float jy1 = __shfl(cy1, jj, 64);
    float jy2 = __shfl(cy2, jj, 64);
    float jar = __shfl(car, jj, 64);
    if (jbase + jj > i) {
      float iw = fminf(ix2, jx2) - fmaxf(ix1, jx1);
      iw = fmaxf(iw, 0.0f);
      float ih = fminf(iy2, jy2) - fmaxf(iy1, jy1);
      ih = fmaxf(ih, 0.0f);
      float inter = iw * ih;
      float uni = ia + jar - inter;
      float iou = inter / fmaxf(uni, 1e-6f);
      if (iou > 0.7f) bits |= (1ull << jj);
    }
  }
  mask[((size_t)b * PRE + i) * NW + cb] = bits;
}

__global__ void mask_prefix_kernel(const float* __restrict__ bx1, const float* __restrict__ bx2,
                                   const float* __restrict__ by1, const float* __restrict__ by2,
                                   const float* __restrict__ bar, u64* __restrict__ mask) {
  int cb = blockIdx.x, rb = blockIdx.y, b = blockIdx.z;
  if (cb < rb) return;
  mask_tile(bx1, bx2, by1, by2, bar, mask, b, rb, cb, threadIdx.x);
}

// fallback: full 4096x4096 mask; 4 column words per 256-thr block (wave each)
__global__ __launch_bounds__(256) void mask_full_kernel(
    const float* __restrict__ bx1, const float* __restrict__ bx2,
    const float* __restrict__ by1, const float* __restrict__ by2,
    const float* __restrict__ bar, u64* __restrict__ mask,
    const int* __restrict__ st_info) {
  int b = blockIdx.z;
  if (st_info[b * 2 + 0] >= POST) return;
  int rb = blockIdx.y;
  int cb = blockIdx.x * 4 + (threadIdx.x >> 6);
  if (cb < rb) return;
  mask_tile(bx1, bx2, by1, by2, bar, mask, b, rb, cb, threadIdx.x & 63);
}

// ---------------- kernel 4: chunked greedy NMS, 4 waves per batch -----------
template<bool FULL>
__global__ __launch_bounds__(256) void nms_kernel_t(
    const u64* __restrict__ mask, u64* __restrict__ keep_words,
    int* __restrict__ st_info) {
  int b = blockIdx.x;
  if (FULL && st_info[b * 2 + 0] >= POST) return;  // hot path already done
  int tid = threadIdx.x;
  int lane = tid & 63;
  int wv = tid >> 6;
  __shared__ u64 part[2][4][64];

  const u64* base = mask + (size_t)b * PRE * NW;
  u64 rem = 0ull, keepw = 0ull;
  int kept = 0;
  const int c1 = FULL ? NW : PREF_CH;

  int c = 0;
  while (c < c1) {
    u64 remc = __shfl(rem, c, 64);
    // ungated row loads for my wave's 16 rows (issue before dependent work)
    const u64* rowp = base + ((size_t)(c * 64 + wv * 16)) * NW + lane;
    u64 m[16];
#pragma unroll
    for (int k = 0; k < 16; ++k) m[k] = rowp[(size_t)k * NW];
    // diagonal word: within-chunk suppression candidates (rare)
    u64 dg = base[((size_t)(c * 64 + lane)) * NW + c];
    u64 nz = __ballot(dg != 0ull);
    while (nz) {
      int i2 = __builtin_ctzll(nz);
      nz &= nz - 1ull;
      u64 di = __shfl(dg, i2, 64);
      if (!((remc >> i2) & 1ull)) remc |= di;
    }
    u64 K = ~remc;  // keep word for this chunk (identical in all waves)
    if (lane == c) keepw = K;
    kept += __popcll(K);

    u32 kb = (u32)((K >> (wv * 16)) & 0xFFFFull);
    u64 acc = 0ull;
#pragma unroll
    for (int k = 0; k < 16; ++k)
      if ((kb >> k) & 1u) acc |= m[k];
    part[c & 1][wv][lane] = acc;
    __syncthreads();
    rem |= part[c & 1][0][lane] | part[c & 1][1][lane] |
           part[c & 1][2][lane] | part[c & 1][3][lane];
    ++c;
    if (kept >= POST) break;  // uniform; later output ranks all >= POST
  }

  if (wv == 0) {
    keep_words[b * 64 + lane] = keepw;  // unprocessed chunks -> 0
    if (!FULL && lane == 0) st_info[b * 2 + 0] = kept;
  }
}

// ---------------- kernel 5: emit first POST kept entries --------------------
__global__ __launch_bounds__(1024) void output_kernel(
    const u64* __restrict__ keep_words, const int* __restrict__ top_idx,
    const float* __restrict__ top_score, const int* __restrict__ labels,
    const float* __restrict__ boxes, float* __restrict__ out) {
  int b = blockIdx.x, tid = threadIdx.x;
  __shared__ u32 scanbuf[1024];
  __shared__ int sh_total;

  u64 w = keep_words[b * 64 + (tid >> 4)];
  u32 my4 = (u32)((w >> ((tid & 15) * 4)) & 0xFull);  // 4 consecutive i per thread
  int cnt = __popc(my4);
  scanbuf[tid] = (u32)cnt;
  __syncthreads();
  for (int off = 1; off < 1024; off <<= 1) {
    u32 v = scanbuf[tid];
    u32 add = (tid >= off) ? scanbuf[tid - off] : 0u;
    __syncthreads();
    scanbuf[tid] = v + add;
    __syncthreads();
  }
  int base = (int)scanbuf[tid] - cnt;
  if (tid == 1023) sh_total = (int)scanbuf[1023];
  __syncthreads();
  int total = sh_total;

  float* rois = out;                 // BB*POST*7
  float* rsc = out + BB * POST * 7;  // BB*POST
  float* rlb = rsc + BB * POST;      // BB*POST (labels as f32)

  int r = 0;
  for (int k = 0; k < 4; ++k) {
    if ((my4 >> k) & 1u) {
      int rank = base + (r++);
      if (rank < POST) {
        int i = tid * 4 + k;
        int idx = top_idx[b * PRE + i];
        const float* bx = boxes + ((size_t)b * NN + idx) * 7;
        float* ro = rois + ((size_t)b * POST + rank) * 7;
        for (int c = 0; c < 7; ++c) ro[c] = bx[c];
        rsc[b * POST + rank] = top_score[b * PRE + i];
        rlb[b * POST + rank] = (float)(labels[b * NN + idx] + 1);
      }
    }
  }
  // invalid slots: rois = 0, score = 0, label = 0 + 1
  for (int s = tid; s < POST; s += 1024) {
    if (s >= total) {
      float* ro = rois + ((size_t)b * POST + s) * 7;
      for (int c = 0; c < 7; ++c) ro[c] = 0.0f;
      rsc[b * POST + s] = 0.0f;
      rlb[b * POST + s] = 1.0f;
    }
  }
}

// ---------------------------------------------------------------------------
extern "C" void kernel_launch(void* const* d_in, const int* in_sizes, int n_in,
                              void* d_out, int out_size, void* d_ws, size_t ws_size,
                              hipStream_t stream) {
  const float* boxes = (const float*)d_in[0];  // (B, N, 7)
  const float* cls = (const float*)d_in[1];    // (B, N, 3)
  float* out = (float*)d_out;                  // rois | scores | labels, flat f32

  char* w = (char*)d_ws;
  float* scores = (float*)w;    w += (size_t)BB * NN * 4;
  int* labels = (int*)w;        w += (size_t)BB * NN * 4;
  int* top_idx = (int*)w;       w += (size_t)BB * PRE * 4;
  float* top_score = (float*)w; w += (size_t)BB * PRE * 4;
  float* bx1 = (float*)w;       w += (size_t)BB * PRE * 4;
  float* bx2 = (float*)w;       w += (size_t)BB * PRE * 4;
  float* by1 = (float*)w;       w += (size_t)BB * PRE * 4;
  float* by2 = (float*)w;       w += (size_t)BB * PRE * 4;
  float* bar = (float*)w;       w += (size_t)BB * PRE * 4;
  u64* mask = (u64*)w;          w += (size_t)BB * PRE * NW * 8;
  u64* keepw = (u64*)w;         w += (size_t)BB * 64 * 8;
  int* st_info = (int*)w;       w += (size_t)BB * 2 * 4;

  // hot path: top-1024 prefix only
  score_kernel<<<(BB * NN + 255) / 256, 256, 0, stream>>>(cls, scores, labels);
  select_kernel_t<PSEL, false><<<BB, 1024, 0, stream>>>(
      scores, boxes, st_info, top_idx, top_score, bx1, bx2, by1, by2, bar);
  mask_prefix_kernel<<<dim3(PREF_CH, PREF_CH, BB), 64, 0, stream>>>(
      bx1, bx2, by1, by2, bar, mask);
  nms_kernel_t<false><<<BB, 256, 0, stream>>>(mask, keepw, st_info);
  // fallback chain (exits immediately when prefix found >= POST keepers)
  select_kernel_t<PRE, true><<<BB, 1024, 0, stream>>>(
      scores, boxes, st_info, top_idx, top_score, bx1, bx2, by1, by2, bar);
  mask_full_kernel<<<dim3(NW / 4, NW, BB), 256, 0, stream>>>(
      bx1, bx2, by1, by2, bar, mask, st_info);
  nms_kernel_t<true><<<BB, 256, 0, stream>>>(mask, keepw, st_info);
  // output
  output_kernel<<<BB, 1024, 0, stream>>>(keepw, top_idx, top_score, labels, boxes, out);
}